// Round 5
// baseline (433.953 us; speedup 1.0000x reference)
//
#include <hip/hip_runtime.h>
#include <hip/hip_bf16.h>
#include <stdint.h>

typedef short short8 __attribute__((ext_vector_type(8)));
typedef float f32x4 __attribute__((ext_vector_type(4)));

__device__ __forceinline__ void gload16(const void* g, void* l) {
  __builtin_amdgcn_global_load_lds((const __attribute__((address_space(1))) void*)g,
                                   (__attribute__((address_space(3))) void*)l, 16, 0, 0);
}

__device__ __forceinline__ unsigned short f2b(float f) {
  unsigned int x = __float_as_uint(f);
  x += 0x7fffu + ((x >> 16) & 1u);
  return (unsigned short)(x >> 16);
}

// ==================== 128x128 2-phase GEMM (QKV projection) ====================
// C[i][j] = sum_k A[i][k] * Bt[j][k]   (A, Bt bf16 row-major), bf16 out.
__global__ __launch_bounds__(256) void gemm_bt(
    const unsigned short* __restrict__ A, const unsigned short* __restrict__ Bt,
    unsigned short* __restrict__ out,
    int M, int N, int K, int lda, int ldb, int ldo)
{
  const int row0 = blockIdx.y * 128;
  const int col0 = blockIdx.x * 128;

  __shared__ __align__(16) char lds[32768];  // A tile [128][64] bf16, B tile after 16KB

  const int tid = threadIdx.x;
  const int wave = tid >> 6;
  const int lane = tid & 63;
  const int wr = wave >> 1, wc = wave & 1;

  const int srow = lane >> 3;
  const int sgrp = (lane & 7) ^ srow;

  const int rA = wr * 64 + (lane & 15);
  const int cB = wc * 64 + (lane & 15);
  const int kb = (lane >> 4) * 16;
  const int xorA = (rA & 7) << 4;
  const int xorB = (cB & 7) << 4;

  f32x4 acc[4][4];
  #pragma unroll
  for (int m = 0; m < 4; ++m)
    #pragma unroll
    for (int n = 0; n < 4; ++n) acc[m][n] = (f32x4)0.0f;

  const int nkt = K >> 6;

  for (int kt = 0; kt < nkt; ++kt) {
    const int kc = kt * 64;
    #pragma unroll
    for (int i = 0; i < 4; ++i) {
      const int ci = wave * 4 + i;
      gload16(A + (long long)(row0 + ci * 8 + srow) * lda + kc + sgrp * 8,
              lds + ci * 1024);
      gload16(Bt + (long long)(col0 + ci * 8 + srow) * ldb + kc + sgrp * 8,
              lds + 16384 + ci * 1024);
    }
    __syncthreads();
    #pragma unroll
    for (int ks = 0; ks < 2; ++ks) {
      short8 af[4], bfr[4];
      #pragma unroll
      for (int m = 0; m < 4; ++m)
        af[m] = *(const short8*)(lds + (rA + m * 16) * 128 + ((ks * 64 + kb) ^ xorA));
      #pragma unroll
      for (int n = 0; n < 4; ++n)
        bfr[n] = *(const short8*)(lds + 16384 + (cB + n * 16) * 128 + ((ks * 64 + kb) ^ xorB));
      #pragma unroll
      for (int m = 0; m < 4; ++m)
        #pragma unroll
        for (int n = 0; n < 4; ++n)
          acc[m][n] = __builtin_amdgcn_mfma_f32_16x16x32_bf16(af[m], bfr[n], acc[m][n], 0, 0, 0);
    }
    __syncthreads();
  }

  const int orow = row0 + wr * 64 + ((lane >> 4) << 2);
  const int ocol = col0 + wc * 64 + (lane & 15);
  #pragma unroll
  for (int m = 0; m < 4; ++m)
    #pragma unroll
    for (int r = 0; r < 4; ++r) {
      const int rg = orow + m * 16 + r;
      #pragma unroll
      for (int n = 0; n < 4; ++n)
        out[(long long)rg * ldo + ocol + n * 16] = f2b(acc[m][n][r]);
    }
}

// ==================== fused flash P+PV ====================
// One block = 32 q-rows of one batch. 8 waves (512 thr).
// Q-tile resident in LDS (swizzled). Loop over causal kv-tiles of 64:
//   S = Q K^T (each wave one 16x16 frag; K B-frags direct from global)
//   p = exp(S/32) masked; per-row sums accumulate in registers (no atomics)
//   P -> swizzled LDS (bf16)
//   O += P Vt^T (per-wave 128-d slice; Vt B-frags direct from global)
// Epilogue: O /= rowsum, fp32 store.
__global__ __launch_bounds__(512) void flash_pv(
    const unsigned short* __restrict__ QKV,  // [B*2048][3072] (Q at 0, K at +1024, V at +2048)
    const unsigned short* __restrict__ Vt,   // [B][1024][2048]
    float* __restrict__ out)                 // [B*2048][1024]
{
  const int qb = blockIdx.x;        // 0..63 q-tile within batch
  const int bz = blockIdx.y;        // batch
  const int q0 = qb * 32;
  const int tid = threadIdx.x;
  const int wave = tid >> 6, lane = tid & 63;
  const int l15 = lane & 15;
  const int lk = lane >> 4;         // 0..3

  __shared__ __align__(16) char qlds[65536];   // Q [32 rows][2048B], XOR-swizzled 16B groups
  __shared__ __align__(16) char plds[4096];    // P [32 rows][128B], XOR-swizzled
  __shared__ float rs2d[4][32];                // per-nw partial row sums

  // ---- stage Q tile ----
  {
    const char* qbase = (const char*)(QKV + (long long)(bz * 2048 + q0) * 3072);
    #pragma unroll
    for (int i = 0; i < 8; ++i) {
      const int c = wave * 8 + i;            // 64 chunks of 1KB
      const int row = c >> 1;
      const int g = (c & 1) * 64 + lane;     // 16B group within 2KB row
      const int src = (g * 16) ^ ((row & 7) << 4);
      gload16(qbase + (long long)row * 6144 + src, qlds + c * 1024);
    }
  }
  __syncthreads();

  const int mw = wave >> 2;        // q half (0..1)
  const int nw = wave & 3;         // kv quarter (0..3)
  const int sa_row = mw * 16 + l15;
  const int sa_xor = (sa_row & 7) << 4;

  f32x4 o[2][8];
  #pragma unroll
  for (int m = 0; m < 2; ++m)
    #pragma unroll
    for (int n = 0; n < 8; ++n) o[m][n] = (f32x4)0.0f;

  float rsacc[4] = {0.f, 0.f, 0.f, 0.f};

  const unsigned short* kbase = QKV + (long long)(bz * 2048) * 3072 + 1024;
  const unsigned short* vtb = Vt + (long long)bz * 1024 * 2048;

  const int jN = (qb >> 1) + 1;
  for (int j = 0; j < jN; ++j) {
    const int t0 = j * 64;
    // ---- S frag: q rows [q0+mw*16, +16), kv cols [t0+nw*16, +16) ----
    const unsigned short* krow = kbase + (long long)(t0 + nw * 16 + l15) * 3072 + lk * 8;
    f32x4 s = (f32x4)0.0f;
    #pragma unroll 8
    for (int dk = 0; dk < 1024; dk += 32) {
      short8 aq = *(const short8*)(qlds + sa_row * 2048 + ((dk * 2 + lk * 16) ^ sa_xor));
      short8 bk = *(const short8*)(krow + dk);
      s = __builtin_amdgcn_mfma_f32_16x16x32_bf16(aq, bk, s, 0, 0, 0);
    }
    // ---- mask + exp + row-partial sums ----
    float p[4];
    const int colg = t0 + nw * 16 + l15;
    #pragma unroll
    for (int r = 0; r < 4; ++r) {
      const int rowg = q0 + mw * 16 + lk * 4 + r;
      p[r] = (colg > rowg) ? 0.0f : __expf(s[r] * 0.03125f);
    }
    float t[4] = {p[0], p[1], p[2], p[3]};
    #pragma unroll
    for (int off = 1; off < 16; off <<= 1)
      #pragma unroll
      for (int r = 0; r < 4; ++r) t[r] += __shfl_xor(t[r], off);
    if (l15 == 0) {
      #pragma unroll
      for (int r = 0; r < 4; ++r) rsacc[r] += t[r];
    }
    __syncthreads();   // previous PV finished reading plds
    #pragma unroll
    for (int r = 0; r < 4; ++r) {
      const int prow = mw * 16 + lk * 4 + r;
      const int pcol = nw * 16 + l15;
      *(unsigned short*)(plds + prow * 128 + ((pcol * 2) ^ ((prow & 7) << 4))) = f2b(p[r]);
    }
    __syncthreads();   // P visible to all waves
    // ---- PV: O[32][wave*128..+128] += P(32x64) . Vt^T ----
    #pragma unroll
    for (int ks = 0; ks < 2; ++ks) {
      short8 pa[2];
      #pragma unroll
      for (int mf = 0; mf < 2; ++mf) {
        const int prow = mf * 16 + l15;
        pa[mf] = *(const short8*)(plds + prow * 128 + ((ks * 64 + lk * 16) ^ ((prow & 7) << 4)));
      }
      #pragma unroll
      for (int nf = 0; nf < 8; ++nf) {
        const int d = wave * 128 + nf * 16 + l15;
        short8 bv = *(const short8*)(vtb + (long long)d * 2048 + t0 + ks * 32 + lk * 8);
        o[0][nf] = __builtin_amdgcn_mfma_f32_16x16x32_bf16(pa[0], bv, o[0][nf], 0, 0, 0);
        o[1][nf] = __builtin_amdgcn_mfma_f32_16x16x32_bf16(pa[1], bv, o[1][nf], 0, 0, 0);
      }
    }
  }

  // ---- rowsum merge (deterministic: one writer per slot) ----
  if (l15 == 0) {
    #pragma unroll
    for (int r = 0; r < 4; ++r) rs2d[nw][mw * 16 + lk * 4 + r] = rsacc[r];
  }
  __syncthreads();

  // ---- epilogue: normalize + store ----
  #pragma unroll
  for (int mf = 0; mf < 2; ++mf) {
    #pragma unroll
    for (int r = 0; r < 4; ++r) {
      const int rowl = mf * 16 + lk * 4 + r;
      const float iv = 1.0f / (rs2d[0][rowl] + rs2d[1][rowl] + rs2d[2][rowl] + rs2d[3][rowl]);
      float* op = out + (long long)(bz * 2048 + q0 + rowl) * 1024 + wave * 128 + l15;
      #pragma unroll
      for (int nf = 0; nf < 8; ++nf)
        op[nf * 16] = o[mf][nf][r] * iv;
    }
  }
}

// fp32 -> bf16 convert, 4 elems/thread
__global__ __launch_bounds__(256) void cvt_x(const float* __restrict__ in,
                                             unsigned short* __restrict__ out, int n4) {
  int i = blockIdx.x * 256 + threadIdx.x;
  if (i >= n4) return;
  const float4 f = ((const float4*)in)[i];
  union { unsigned short u[4]; uint2 v; } o;
  o.u[0] = f2b(f.x); o.u[1] = f2b(f.y); o.u[2] = f2b(f.z); o.u[3] = f2b(f.w);
  ((uint2*)out)[i] = o.v;
}

// W [1024][1024] fp32 -> Wt bf16 transposed; 3 matrices (z) into contiguous [3072][1024]
__global__ __launch_bounds__(256) void cvt_w(
    const float* __restrict__ W0, const float* __restrict__ W1, const float* __restrict__ W2,
    unsigned short* __restrict__ O) {
  const float* W = blockIdx.z == 0 ? W0 : (blockIdx.z == 1 ? W1 : W2);
  unsigned short* Oz = O + (long long)blockIdx.z * 1024 * 1024;
  __shared__ float t[32][33];
  const int tx = threadIdx.x, ty = threadIdx.y;
  const int x = blockIdx.x * 32 + tx;
  const int y0 = blockIdx.y * 32;
  #pragma unroll
  for (int i = 0; i < 4; ++i)
    t[ty + i * 8][tx] = W[(long long)(y0 + ty + i * 8) * 1024 + x];
  __syncthreads();
  const int xo = blockIdx.y * 32 + tx;
  const int yo0 = blockIdx.x * 32;
  #pragma unroll
  for (int i = 0; i < 4; ++i)
    Oz[(long long)(yo0 + ty + i * 8) * 1024 + xo] = f2b(t[tx][ty + i * 8]);
}

// Vt[b][d][t] = QKV[b*2048+t][2048+d]
__global__ __launch_bounds__(256) void vtrans(const unsigned short* __restrict__ QKV,
                                              unsigned short* __restrict__ Vt) {
  __shared__ unsigned short t[32][33];
  const int tx = threadIdx.x, ty = threadIdx.y;  // 32x8
  const int b = blockIdx.z;
  const int t0 = blockIdx.x * 32;
  const int d0 = blockIdx.y * 32;
  #pragma unroll
  for (int i = 0; i < 4; ++i)
    t[ty + i * 8][tx] = QKV[(long long)(b * 2048 + t0 + ty + i * 8) * 3072 + 2048 + d0 + tx];
  __syncthreads();
  #pragma unroll
  for (int i = 0; i < 4; ++i)
    Vt[((long long)b * 1024 + d0 + ty + i * 8) * 2048 + t0 + tx] = t[tx][ty + i * 8];
}

extern "C" void kernel_launch(void* const* d_in, const int* in_sizes, int n_in,
                              void* d_out, int out_size, void* d_ws, size_t ws_size,
                              hipStream_t stream) {
  (void)in_sizes; (void)n_in; (void)out_size; (void)ws_size;
  const float* x  = (const float*)d_in[0];
  const float* Wq = (const float*)d_in[1];
  const float* Wk = (const float*)d_in[2];
  const float* Wv = (const float*)d_in[3];
  float* out = (float*)d_out;

  char* ws = (char*)d_ws;
  unsigned short* xb  = (unsigned short*)(ws);               // 8192x1024 bf16
  unsigned short* Wt  = (unsigned short*)(ws + 16777216);    // 3072x1024 bf16
  unsigned short* QKV = (unsigned short*)(ws + 33554432);    // 8192x3072 bf16
  unsigned short* Vt  = (unsigned short*)(ws + 83886080);    // 4x1024x2048 bf16

  // 1. dtype conversions
  cvt_x<<<8192, 256, 0, stream>>>(x, xb, 2097152);
  cvt_w<<<dim3(32, 32, 3), dim3(32, 8), 0, stream>>>(Wq, Wk, Wv, Wt);

  // 2. fused QKV = x . Wt^T  [8192][3072]  (proven 2-phase 128^2)
  gemm_bt<<<dim3(24, 64, 1), 256, 0, stream>>>(xb, Wt, QKV,
      8192, 3072, 1024, 1024, 1024, 3072);

  // 3. V section -> Vt [b][1024][2048]
  vtrans<<<dim3(64, 32, 4), dim3(32, 8), 0, stream>>>(QKV, Vt);

  // 4. fused causal softmax-attention: out = softmax(QK^T/32) V
  flash_pv<<<dim3(64, 4), 512, 0, stream>>>(QKV, Vt, out);
}

// Round 6
// 194.340 us; speedup vs baseline: 2.2330x; 2.2330x over previous
//
#include <hip/hip_runtime.h>
#include <hip/hip_bf16.h>
#include <stdint.h>

typedef short short8 __attribute__((ext_vector_type(8)));
typedef float f32x4 __attribute__((ext_vector_type(4)));

__device__ __forceinline__ void gload16(const void* g, void* l) {
  __builtin_amdgcn_global_load_lds((const __attribute__((address_space(1))) void*)g,
                                   (__attribute__((address_space(3))) void*)l, 16, 0, 0);
}

__device__ __forceinline__ unsigned short f2b(float f) {
  unsigned int x = __float_as_uint(f);
  x += 0x7fffu + ((x >> 16) & 1u);
  return (unsigned short)(x >> 16);
}

// ==================== 128x128 2-phase GEMM ====================
// C[i][j] = sum_k A[i][k] * Bt[j][k]   (A, Bt bf16 row-major)
// MODE 0: plain bf16 out.
// MODE 1: causal exp(s/32) bf16 out (skip upper tiles) + rowsum atomics.
// MODE 2: fp32 out scaled by 1/sums[row], K-loop bounded causally.
template<int MODE>
__global__ __launch_bounds__(256) void gemm_bt(
    const unsigned short* __restrict__ A, const unsigned short* __restrict__ Bt,
    void* __restrict__ outv, float* __restrict__ sums,
    int M, int N, int K,
    long long aZ, long long bZ, long long oZ,
    int lda, int ldb, int ldo)
{
  const int z = blockIdx.z;
  const int row0 = blockIdx.y * 128;
  const int col0 = blockIdx.x * 128;
  if (MODE == 1 && col0 > row0 + 127) return;

  const unsigned short* Az = A + (long long)z * aZ;
  const unsigned short* Bz = Bt + (long long)z * bZ;

  __shared__ __align__(16) char lds[32768];  // A tile [128][64] bf16, B tile after 16KB

  const int tid = threadIdx.x;
  const int wave = tid >> 6;
  const int lane = tid & 63;
  const int wr = wave >> 1, wc = wave & 1;

  // staging: source col-group XOR-swizzled so linear LDS dest ends up swizzled
  const int srow = lane >> 3;
  const int sgrp = (lane & 7) ^ srow;

  const int rA = wr * 64 + (lane & 15);
  const int cB = wc * 64 + (lane & 15);
  const int kb = (lane >> 4) * 16;
  const int xorA = (rA & 7) << 4;
  const int xorB = (cB & 7) << 4;

  f32x4 acc[4][4];
  #pragma unroll
  for (int m = 0; m < 4; ++m)
    #pragma unroll
    for (int n = 0; n < 4; ++n) acc[m][n] = (f32x4)0.0f;

  int kEnd = K;
  if (MODE == 2) kEnd = min(K, row0 + 128);
  const int nkt = kEnd >> 6;

  for (int kt = 0; kt < nkt; ++kt) {
    const int kc = kt * 64;
    #pragma unroll
    for (int i = 0; i < 4; ++i) {
      const int ci = wave * 4 + i;
      gload16(Az + (long long)(row0 + ci * 8 + srow) * lda + kc + sgrp * 8,
              lds + ci * 1024);
      gload16(Bz + (long long)(col0 + ci * 8 + srow) * ldb + kc + sgrp * 8,
              lds + 16384 + ci * 1024);
    }
    __syncthreads();
    #pragma unroll
    for (int ks = 0; ks < 2; ++ks) {
      short8 af[4], bfr[4];
      #pragma unroll
      for (int m = 0; m < 4; ++m)
        af[m] = *(const short8*)(lds + (rA + m * 16) * 128 + ((ks * 64 + kb) ^ xorA));
      #pragma unroll
      for (int n = 0; n < 4; ++n)
        bfr[n] = *(const short8*)(lds + 16384 + (cB + n * 16) * 128 + ((ks * 64 + kb) ^ xorB));
      #pragma unroll
      for (int m = 0; m < 4; ++m)
        #pragma unroll
        for (int n = 0; n < 4; ++n)
          acc[m][n] = __builtin_amdgcn_mfma_f32_16x16x32_bf16(af[m], bfr[n], acc[m][n], 0, 0, 0);
    }
    __syncthreads();
  }

  const int orow = row0 + wr * 64 + ((lane >> 4) << 2);
  const int ocol = col0 + wc * 64 + (lane & 15);
  if (MODE == 2) {
    float* out = (float*)outv + (long long)z * oZ;
    const float* sz = sums + (long long)z * M;
    #pragma unroll
    for (int m = 0; m < 4; ++m)
      #pragma unroll
      for (int r = 0; r < 4; ++r) {
        const int rg = orow + m * 16 + r;
        const float iv = 1.0f / sz[rg];
        #pragma unroll
        for (int n = 0; n < 4; ++n)
          out[(long long)rg * ldo + ocol + n * 16] = acc[m][n][r] * iv;
      }
  } else if (MODE == 1) {
    unsigned short* out = (unsigned short*)outv + (long long)z * oZ;
    #pragma unroll
    for (int m = 0; m < 4; ++m)
      #pragma unroll
      for (int r = 0; r < 4; ++r) {
        const int rg = orow + m * 16 + r;
        float rs = 0.f;
        #pragma unroll
        for (int n = 0; n < 4; ++n) {
          const int cg = ocol + n * 16;
          float p = (cg > rg) ? 0.0f : __expf(acc[m][n][r] * 0.03125f);
          rs += p;
          out[(long long)rg * ldo + cg] = f2b(p);
        }
        #pragma unroll
        for (int off = 1; off < 16; off <<= 1) rs += __shfl_xor(rs, off);
        if ((lane & 15) == 0) atomicAdd(&sums[(long long)z * M + rg], rs);
      }
  } else {
    unsigned short* out = (unsigned short*)outv + (long long)z * oZ;
    #pragma unroll
    for (int m = 0; m < 4; ++m)
      #pragma unroll
      for (int r = 0; r < 4; ++r) {
        const int rg = orow + m * 16 + r;
        #pragma unroll
        for (int n = 0; n < 4; ++n)
          out[(long long)rg * ldo + ocol + n * 16] = f2b(acc[m][n][r]);
      }
  }
}

// fp32 -> bf16 convert, 4 elems/thread (used for x, Wq, Wk)
__global__ __launch_bounds__(256) void cvt_x(const float* __restrict__ in,
                                             unsigned short* __restrict__ out, int n4) {
  int i = blockIdx.x * 256 + threadIdx.x;
  if (i >= n4) return;
  const float4 f = ((const float4*)in)[i];
  union { unsigned short u[4]; uint2 v; } o;
  o.u[0] = f2b(f.x); o.u[1] = f2b(f.y); o.u[2] = f2b(f.z); o.u[3] = f2b(f.w);
  ((uint2*)out)[i] = o.v;
}

// W [1024][1024] fp32 -> O bf16 transposed [1024][1024]
__global__ __launch_bounds__(256) void cvt_wt(const float* __restrict__ W,
                                              unsigned short* __restrict__ O) {
  __shared__ float t[32][33];
  const int tx = threadIdx.x, ty = threadIdx.y;  // 32x8
  const int x = blockIdx.x * 32 + tx;
  const int y0 = blockIdx.y * 32;
  #pragma unroll
  for (int i = 0; i < 4; ++i)
    t[ty + i * 8][tx] = W[(long long)(y0 + ty + i * 8) * 1024 + x];
  __syncthreads();
  const int xo = blockIdx.y * 32 + tx;
  const int yo0 = blockIdx.x * 32;
  #pragma unroll
  for (int i = 0; i < 4; ++i)
    O[(long long)(yo0 + ty + i * 8) * 1024 + xo] = f2b(t[tx][ty + i * 8]);
}

// Vt[b][d][t] = yV[(b*2048+t)][1024+d]  (transpose of the V half of yV)
__global__ __launch_bounds__(256) void vtrans(const unsigned short* __restrict__ yV,
                                              unsigned short* __restrict__ Vt) {
  __shared__ unsigned short t[32][33];
  const int tx = threadIdx.x, ty = threadIdx.y;  // 32x8
  const int b = blockIdx.z;
  const int t0 = blockIdx.x * 32;
  const int d0 = blockIdx.y * 32;
  #pragma unroll
  for (int i = 0; i < 4; ++i)
    t[ty + i * 8][tx] = yV[(long long)(b * 2048 + t0 + ty + i * 8) * 2048 + 1024 + d0 + tx];
  __syncthreads();
  #pragma unroll
  for (int i = 0; i < 4; ++i)
    Vt[((long long)b * 1024 + d0 + ty + i * 8) * 2048 + t0 + tx] = t[tx][ty + i * 8];
}

extern "C" void kernel_launch(void* const* d_in, const int* in_sizes, int n_in,
                              void* d_out, int out_size, void* d_ws, size_t ws_size,
                              hipStream_t stream) {
  (void)in_sizes; (void)n_in; (void)out_size; (void)ws_size;
  const float* x  = (const float*)d_in[0];
  const float* Wq = (const float*)d_in[1];
  const float* Wk = (const float*)d_in[2];
  const float* Wv = (const float*)d_in[3];
  float* out = (float*)d_out;

  char* ws = (char*)d_ws;
  unsigned short* xb  = (unsigned short*)(ws);               // 8192x1024 bf16 : 16.78 MB
  unsigned short* Wqb = (unsigned short*)(ws + 16777216);    // 1024x1024 bf16
  unsigned short* Wkb = (unsigned short*)(ws + 18874368);    // 1024x1024 bf16
  unsigned short* Wt2 = (unsigned short*)(ws + 20971520);    // [2048][1024] bf16: rows 0-1023 = M^T, 1024-2047 = Wv^T
  unsigned short* yV  = (unsigned short*)(ws + 25165824);    // 8192x2048 bf16 : 33.55 MB (y | V)
  unsigned short* Vt  = (unsigned short*)(ws + 58720256);    // 4x1024x2048 bf16 : 16.78 MB
  unsigned short* P   = (unsigned short*)(ws + 75497472);    // 4x2048x2048 bf16 : 33.55 MB
  float*          sums = (float*)(ws + 109051904);           // 4x2048 fp32

  hipMemsetAsync(sums, 0, 4 * 2048 * sizeof(float), stream);

  // 1. dtype conversions: x, Wq, Wk plain; Wv transposed into Wt2's V half
  cvt_x<<<8192, 256, 0, stream>>>(x, xb, 2097152);
  cvt_x<<<1024, 256, 0, stream>>>(Wq, Wqb, 262144);
  cvt_x<<<1024, 256, 0, stream>>>(Wk, Wkb, 262144);
  cvt_wt<<<dim3(32, 32), dim3(32, 8), 0, stream>>>(Wv, Wt2 + 1024 * 1024);

  // 2. M^T = Wk . Wq^T  (so that y = x.M uses Bt = M^T row-major)
  gemm_bt<0><<<dim3(8, 8, 1), 256, 0, stream>>>(Wkb, Wqb, Wt2, nullptr,
      1024, 1024, 1024, 0, 0, 0, 1024, 1024, 1024);

  // 3. [y | V] = x . [M^T ; Wv^T]^T  -> [8192][2048]
  gemm_bt<0><<<dim3(16, 64, 1), 256, 0, stream>>>(xb, Wt2, yV, nullptr,
      8192, 2048, 1024, 0, 0, 0, 1024, 1024, 2048);

  // 4. V half -> Vt [b][1024][2048]
  vtrans<<<dim3(64, 32, 4), dim3(32, 8), 0, stream>>>(yV, Vt);

  // 5. P = exp((y x^T)/32) causal, unnormalized bf16 + rowsums
  //    (S = x M x^T == Q K^T exactly)
  gemm_bt<1><<<dim3(16, 16, 4), 256, 0, stream>>>(yV, xb, P, sums,
      2048, 2048, 1024, (long long)2048 * 2048, (long long)2048 * 1024,
      (long long)2048 * 2048, 2048, 1024, 2048);

  // 6. context = (P Vt^T) / rowsum  (fp32 out, causal K-bound)
  gemm_bt<2><<<dim3(8, 16, 4), 256, 0, stream>>>(P, Vt, out, sums,
      2048, 1024, 2048, (long long)2048 * 2048, (long long)1024 * 2048,
      (long long)2048 * 1024, 2048, 2048, 1024);
}

// Round 7
// 173.907 us; speedup vs baseline: 2.4953x; 1.1175x over previous
//
#include <hip/hip_runtime.h>
#include <hip/hip_bf16.h>
#include <stdint.h>

typedef short short8 __attribute__((ext_vector_type(8)));
typedef short short4v __attribute__((ext_vector_type(4)));
typedef float f32x4 __attribute__((ext_vector_type(4)));

__device__ __forceinline__ void gload16(const void* g, void* l) {
  __builtin_amdgcn_global_load_lds((const __attribute__((address_space(1))) void*)g,
                                   (__attribute__((address_space(3))) void*)l, 16, 0, 0);
}

__device__ __forceinline__ unsigned short f2b(float f) {
  unsigned int x = __float_as_uint(f);
  x += 0x7fffu + ((x >> 16) & 1u);
  return (unsigned short)(x >> 16);
}

// ==================== 128x128 2-phase GEMM ====================
// C[i][j] = sum_k A[i][k] * Bt[j][k]   (A, Bt bf16 row-major)
// MODE 0: plain bf16 out.
// MODE 2: fp32 out scaled by 1/sums[row], K-loop bounded causally.
// MODE 3: col0<1024 -> bf16 out (y); col0>=1024 -> write acc TRANSPOSED to vt
//         (Vt[b][d][t], d = col-1024, b = row0>>11, t = row within batch).
template<int MODE>
__global__ __launch_bounds__(256) void gemm_bt(
    const unsigned short* __restrict__ A, const unsigned short* __restrict__ Bt,
    void* __restrict__ outv, float* __restrict__ sums, unsigned short* __restrict__ vt,
    int M, int N, int K,
    long long aZ, long long bZ, long long oZ,
    int lda, int ldb, int ldo)
{
  const int z = blockIdx.z;
  const int row0 = blockIdx.y * 128;
  const int col0 = blockIdx.x * 128;

  const unsigned short* Az = A + (long long)z * aZ;
  const unsigned short* Bz = Bt + (long long)z * bZ;

  __shared__ __align__(16) char lds[32768];  // A tile [128][64] bf16, B tile after 16KB

  const int tid = threadIdx.x;
  const int wave = tid >> 6;
  const int lane = tid & 63;
  const int wr = wave >> 1, wc = wave & 1;
  const int l15 = lane & 15, lk = lane >> 4;

  // staging: source col-group XOR-swizzled so linear LDS dest ends up swizzled
  const int srow = lane >> 3;
  const int sgrp = (lane & 7) ^ srow;

  const int rA = wr * 64 + l15;
  const int cB = wc * 64 + l15;
  const int kb = lk * 16;
  const int xorA = (rA & 7) << 4;
  const int xorB = (cB & 7) << 4;

  f32x4 acc[4][4];
  #pragma unroll
  for (int m = 0; m < 4; ++m)
    #pragma unroll
    for (int n = 0; n < 4; ++n) acc[m][n] = (f32x4)0.0f;

  int kEnd = K;
  if (MODE == 2) kEnd = min(K, row0 + 128);
  const int nkt = kEnd >> 6;

  for (int kt = 0; kt < nkt; ++kt) {
    const int kc = kt * 64;
    #pragma unroll
    for (int i = 0; i < 4; ++i) {
      const int ci = wave * 4 + i;
      gload16(Az + (long long)(row0 + ci * 8 + srow) * lda + kc + sgrp * 8,
              lds + ci * 1024);
      gload16(Bz + (long long)(col0 + ci * 8 + srow) * ldb + kc + sgrp * 8,
              lds + 16384 + ci * 1024);
    }
    __syncthreads();
    #pragma unroll
    for (int ks = 0; ks < 2; ++ks) {
      short8 af[4], bfr[4];
      #pragma unroll
      for (int m = 0; m < 4; ++m)
        af[m] = *(const short8*)(lds + (rA + m * 16) * 128 + ((ks * 64 + kb) ^ xorA));
      #pragma unroll
      for (int n = 0; n < 4; ++n)
        bfr[n] = *(const short8*)(lds + 16384 + (cB + n * 16) * 128 + ((ks * 64 + kb) ^ xorB));
      #pragma unroll
      for (int m = 0; m < 4; ++m)
        #pragma unroll
        for (int n = 0; n < 4; ++n)
          acc[m][n] = __builtin_amdgcn_mfma_f32_16x16x32_bf16(af[m], bfr[n], acc[m][n], 0, 0, 0);
    }
    __syncthreads();
  }

  const int orow = row0 + wr * 64 + lk * 4;
  const int ocol = col0 + wc * 64 + l15;
  if (MODE == 2) {
    float* out = (float*)outv + (long long)z * oZ;
    const float* sz = sums + (long long)z * M;
    #pragma unroll
    for (int m = 0; m < 4; ++m)
      #pragma unroll
      for (int r = 0; r < 4; ++r) {
        const int rg = orow + m * 16 + r;
        const float iv = 1.0f / sz[rg];
        #pragma unroll
        for (int n = 0; n < 4; ++n)
          out[(long long)rg * ldo + ocol + n * 16] = acc[m][n][r] * iv;
      }
  } else if (MODE == 3 && col0 >= 1024) {
    // transposed write: Vt[b][d][t]
    const int b = row0 >> 11;
    const int t0 = (row0 & 2047) + wr * 64 + lk * 4;
    const int d0 = (col0 - 1024) + wc * 64 + l15;
    #pragma unroll
    for (int n = 0; n < 4; ++n) {
      const int d = d0 + n * 16;
      unsigned short* vrow = vt + ((long long)b * 1024 + d) * 2048 + t0;
      #pragma unroll
      for (int m = 0; m < 4; ++m) {
        short4v v;
        v[0] = (short)f2b(acc[m][n][0]);
        v[1] = (short)f2b(acc[m][n][1]);
        v[2] = (short)f2b(acc[m][n][2]);
        v[3] = (short)f2b(acc[m][n][3]);
        *(short4v*)(vrow + m * 16) = v;
      }
    }
  } else {
    unsigned short* out = (unsigned short*)outv + (long long)z * oZ;
    #pragma unroll
    for (int m = 0; m < 4; ++m)
      #pragma unroll
      for (int r = 0; r < 4; ++r) {
        const int rg = orow + m * 16 + r;
        #pragma unroll
        for (int n = 0; n < 4; ++n)
          out[(long long)rg * ldo + ocol + n * 16] = f2b(acc[m][n][r]);
      }
  }
}

// ==================== 256x256 8-phase GEMM (causal P) ====================
// MODE 1: causal exp(s/32) bf16 out (skip upper tiles) + rowsum atomics.
#define STG(buf, isB, half, kt) do {                                           \
    const unsigned short* _s = (isB) ? Bz : Az;                                \
    const int _ld = (isB) ? ldb : lda;                                         \
    const int _b0 = (isB) ? col0 : row0;                                       \
    char* _d = lds + (buf) * 65536 + (isB) * 32768 + (half) * 16384;           \
    _Pragma("unroll")                                                          \
    for (int _i = 0; _i < 2; ++_i) {                                           \
      const int _c = wave * 2 + _i;                                            \
      const int _row = (half) * 128 + _c * 8 + srow;                           \
      gload16(_s + (long long)(_b0 + _row) * _ld + (kt) * 64 + sgrp * 8,       \
              _d + _c * 1024);                                                 \
    } } while (0)

#define LDA8(dst, buf, mh) do {                                                \
    _Pragma("unroll")                                                          \
    for (int _m = 0; _m < 4; ++_m) {                                           \
      const int _r = wr * 128 + ((mh) * 4 + _m) * 16 + (lane & 15);            \
      const char* _p = lds + (buf) * 65536 + _r * 128;                         \
      const int _x = (_r & 7) << 4;                                            \
      dst[_m][0] = *(const short8*)(_p + ((kbyte) ^ _x));                      \
      dst[_m][1] = *(const short8*)(_p + ((64 + kbyte) ^ _x));                 \
    } } while (0)

#define LDB4(dst, buf, nh) do {                                                \
    _Pragma("unroll")                                                          \
    for (int _n = 0; _n < 2; ++_n) {                                           \
      const int _r = wc * 64 + ((nh) * 2 + _n) * 16 + (lane & 15);             \
      const char* _p = lds + (buf) * 65536 + 32768 + _r * 128;                 \
      const int _x = (_r & 7) << 4;                                            \
      dst[_n][0] = *(const short8*)(_p + ((kbyte) ^ _x));                      \
      dst[_n][1] = *(const short8*)(_p + ((64 + kbyte) ^ _x));                 \
    } } while (0)

#define MFMA16(mh, nh, av, bv) do {                                            \
    __builtin_amdgcn_s_setprio(1);                                             \
    _Pragma("unroll") for (int _n = 0; _n < 2; ++_n)                           \
    _Pragma("unroll") for (int _m = 0; _m < 4; ++_m)                           \
    _Pragma("unroll") for (int _k = 0; _k < 2; ++_k)                           \
      acc[(mh)*4+_m][(nh)*2+_n] = __builtin_amdgcn_mfma_f32_16x16x32_bf16(     \
          av[_m][_k], bv[_n][_k], acc[(mh)*4+_m][(nh)*2+_n], 0, 0, 0);         \
    __builtin_amdgcn_s_setprio(0);                                             \
  } while (0)

#define BAR() __builtin_amdgcn_s_barrier()
#define VM4() asm volatile("s_waitcnt vmcnt(4)" ::: "memory")
#define VM0() asm volatile("s_waitcnt vmcnt(0)" ::: "memory")

__global__ __launch_bounds__(512, 2) void gemm8_p(
    const unsigned short* __restrict__ A, const unsigned short* __restrict__ Bt,
    unsigned short* __restrict__ outp, float* __restrict__ sums,
    int M, int K,
    long long aZ, long long bZ, long long oZ,
    int lda, int ldb, int ldo)
{
  const int z = blockIdx.z;
  const int row0 = blockIdx.y * 256;
  const int col0 = blockIdx.x * 256;
  if (col0 > row0 + 255) return;

  const unsigned short* Az = A + (long long)z * aZ;
  const unsigned short* Bz = Bt + (long long)z * bZ;

  __shared__ __align__(16) char lds[131072];

  const int tid = threadIdx.x;
  const int wave = tid >> 6, lane = tid & 63;
  const int wr = wave >> 2, wc = wave & 3;
  const int srow = lane >> 3, sgrp = (lane & 7) ^ srow;
  const int kbyte = (lane >> 4) * 16;

  const int nt = K >> 7;

  f32x4 acc[8][4];
  #pragma unroll
  for (int m = 0; m < 8; ++m)
    #pragma unroll
    for (int n = 0; n < 4; ++n) acc[m][n] = (f32x4)0.0f;

  short8 a[4][2], b0[2][2], b1[2][2];

  STG(0, 1, 0, 0); STG(0, 1, 1, 0); STG(0, 0, 0, 0); STG(0, 0, 1, 0);
  STG(1, 1, 0, 1); STG(1, 1, 1, 1);
  VM4(); BAR();

  for (int t = 0; t < nt; ++t) {
    const bool pf = (t < nt - 1);
    LDA8(a, 0, 0); LDB4(b0, 0, 0);
    STG(1, 0, 0, 2 * t + 1);
    BAR(); MFMA16(0, 0, a, b0); BAR();
    LDB4(b1, 0, 1);
    STG(1, 0, 1, 2 * t + 1);
    BAR(); MFMA16(0, 1, a, b1); BAR();
    LDA8(a, 0, 1);
    if (pf) STG(0, 1, 0, 2 * t + 2);
    BAR(); MFMA16(1, 1, a, b1); BAR();
    if (pf) STG(0, 1, 1, 2 * t + 2);
    BAR(); MFMA16(1, 0, a, b0);
    if (pf) VM4(); else VM0();
    BAR();
    LDA8(a, 1, 0); LDB4(b0, 1, 0);
    if (pf) STG(0, 0, 0, 2 * t + 2);
    BAR(); MFMA16(0, 0, a, b0); BAR();
    LDB4(b1, 1, 1);
    if (pf) STG(0, 0, 1, 2 * t + 2);
    BAR(); MFMA16(0, 1, a, b1); BAR();
    LDA8(a, 1, 1);
    if (pf) STG(1, 1, 0, 2 * t + 3);
    BAR(); MFMA16(1, 1, a, b1); BAR();
    if (pf) STG(1, 1, 1, 2 * t + 3);
    BAR(); MFMA16(1, 0, a, b0);
    if (pf) VM4();
    BAR();
  }

  const int orow = row0 + wr * 128 + ((lane >> 4) << 2);
  const int ocol = col0 + wc * 64 + (lane & 15);
  unsigned short* out = outp + (long long)z * oZ;
  #pragma unroll
  for (int m = 0; m < 8; ++m)
    #pragma unroll
    for (int r = 0; r < 4; ++r) {
      const int rg = orow + m * 16 + r;
      float rs = 0.f;
      #pragma unroll
      for (int n = 0; n < 4; ++n) {
        const int cg = ocol + n * 16;
        float p = (cg > rg) ? 0.0f : __expf(acc[m][n][r] * 0.03125f);
        rs += p;
        out[(long long)rg * ldo + cg] = f2b(p);
      }
      #pragma unroll
      for (int off = 1; off < 16; off <<= 1) rs += __shfl_xor(rs, off);
      if ((lane & 15) == 0) atomicAdd(&sums[(long long)z * M + rg], rs);
    }
}

// fp32 -> bf16 convert, 4 elems/thread
__global__ __launch_bounds__(256) void cvt_x(const float* __restrict__ in,
                                             unsigned short* __restrict__ out, int n4) {
  int i = blockIdx.x * 256 + threadIdx.x;
  if (i >= n4) return;
  const float4 f = ((const float4*)in)[i];
  union { unsigned short u[4]; uint2 v; } o;
  o.u[0] = f2b(f.x); o.u[1] = f2b(f.y); o.u[2] = f2b(f.z); o.u[3] = f2b(f.w);
  ((uint2*)out)[i] = o.v;
}

// W [1024][1024] fp32 -> O bf16 transposed [1024][1024]
__global__ __launch_bounds__(256) void cvt_wt(const float* __restrict__ W,
                                              unsigned short* __restrict__ O) {
  __shared__ float t[32][33];
  const int tx = threadIdx.x, ty = threadIdx.y;  // 32x8
  const int x = blockIdx.x * 32 + tx;
  const int y0 = blockIdx.y * 32;
  #pragma unroll
  for (int i = 0; i < 4; ++i)
    t[ty + i * 8][tx] = W[(long long)(y0 + ty + i * 8) * 1024 + x];
  __syncthreads();
  const int xo = blockIdx.y * 32 + tx;
  const int yo0 = blockIdx.x * 32;
  #pragma unroll
  for (int i = 0; i < 4; ++i)
    O[(long long)(yo0 + ty + i * 8) * 1024 + xo] = f2b(t[tx][ty + i * 8]);
}

extern "C" void kernel_launch(void* const* d_in, const int* in_sizes, int n_in,
                              void* d_out, int out_size, void* d_ws, size_t ws_size,
                              hipStream_t stream) {
  (void)in_sizes; (void)n_in; (void)out_size; (void)ws_size;
  const float* x  = (const float*)d_in[0];
  const float* Wq = (const float*)d_in[1];
  const float* Wk = (const float*)d_in[2];
  const float* Wv = (const float*)d_in[3];
  float* out = (float*)d_out;

  char* ws = (char*)d_ws;
  unsigned short* xb  = (unsigned short*)(ws);               // 8192x1024 bf16 : 16.78 MB
  unsigned short* Wqb = (unsigned short*)(ws + 16777216);    // 1024x1024 bf16
  unsigned short* Wkb = (unsigned short*)(ws + 18874368);    // 1024x1024 bf16
  unsigned short* Wt2 = (unsigned short*)(ws + 20971520);    // [2048][1024]: M^T ; Wv^T
  unsigned short* y   = (unsigned short*)(ws + 25165824);    // 8192x1024 bf16 : 16.78 MB
  unsigned short* Vt  = (unsigned short*)(ws + 41943040);    // 4x1024x2048 bf16 : 16.78 MB
  unsigned short* P   = (unsigned short*)(ws + 58720256);    // 4x2048x2048 bf16 : 33.55 MB
  float*          sums = (float*)(ws + 92274688);            // 4x2048 fp32

  hipMemsetAsync(sums, 0, 4 * 2048 * sizeof(float), stream);

  // 1. dtype conversions: x, Wq, Wk plain bf16; Wv transposed into Wt2's V half
  cvt_x<<<8192, 256, 0, stream>>>(x, xb, 2097152);
  cvt_x<<<1024, 256, 0, stream>>>(Wq, Wqb, 262144);
  cvt_x<<<1024, 256, 0, stream>>>(Wk, Wkb, 262144);
  cvt_wt<<<dim3(32, 32), dim3(32, 8), 0, stream>>>(Wv, Wt2 + 1024 * 1024);

  // 2. M^T = Wk . Wq^T   (y = x.M replaces both Q and K projections)
  gemm_bt<0><<<dim3(8, 8, 1), 256, 0, stream>>>(Wkb, Wqb, Wt2, nullptr, nullptr,
      1024, 1024, 1024, 0, 0, 0, 1024, 1024, 1024);

  // 3. [y | V] = x . [M^T ; Wv^T]^T ; y half -> y row-major, V half -> Vt transposed
  gemm_bt<3><<<dim3(16, 64, 1), 256, 0, stream>>>(xb, Wt2, y, nullptr, Vt,
      8192, 2048, 1024, 0, 0, 0, 1024, 1024, 1024);

  // 4. P = exp((y x^T)/32) causal, unnormalized bf16 + rowsums  (8-phase 256^2)
  gemm8_p<<<dim3(8, 8, 4), 512, 0, stream>>>(y, xb, P, sums,
      2048, 1024, (long long)2048 * 1024, (long long)2048 * 1024,
      (long long)2048 * 2048, 1024, 1024, 2048);

  // 5. context = (P Vt^T) / rowsum  (fp32 out, causal K-bound)
  gemm_bt<2><<<dim3(8, 16, 4), 256, 0, stream>>>(P, Vt, out, sums, nullptr,
      2048, 1024, 2048, (long long)2048 * 2048, (long long)1024 * 2048,
      (long long)2048 * 1024, 2048, 2048, 1024);
}

// Round 8
// 156.685 us; speedup vs baseline: 2.7696x; 1.1099x over previous
//
#include <hip/hip_runtime.h>
#include <hip/hip_bf16.h>
#include <stdint.h>

typedef short short8 __attribute__((ext_vector_type(8)));
typedef short short4v __attribute__((ext_vector_type(4)));
typedef float f32x4 __attribute__((ext_vector_type(4)));

__device__ __forceinline__ void gload16(const void* g, void* l) {
  __builtin_amdgcn_global_load_lds((const __attribute__((address_space(1))) void*)g,
                                   (__attribute__((address_space(3))) void*)l, 16, 0, 0);
}

__device__ __forceinline__ unsigned short f2b(float f) {
  unsigned int x = __float_as_uint(f);
  x += 0x7fffu + ((x >> 16) & 1u);
  return (unsigned short)(x >> 16);
}

// ==================== prep: cvt x, transpose Wv, M^T GEMM, zero sums ====================
// flat grid: [0,8192) cvt x->xb | [8192,9216) Wv->Wt2_V^T | [9216,9472) M^T=Wk.Wq^T | [9472,9504) sums=0
__global__ __launch_bounds__(256) void prep(
    const float* __restrict__ x, const float* __restrict__ Wq,
    const float* __restrict__ Wk, const float* __restrict__ Wv,
    unsigned short* __restrict__ xb, unsigned short* __restrict__ Wt2,
    float* __restrict__ sums)
{
  __shared__ __align__(16) char smem[16384];
  const int bid = blockIdx.x;
  const int tid = threadIdx.x;
  if (bid < 8192) {
    const int i = bid * 256 + tid;
    const float4 f = ((const float4*)x)[i];
    union { unsigned short u[4]; uint2 v; } o;
    o.u[0] = f2b(f.x); o.u[1] = f2b(f.y); o.u[2] = f2b(f.z); o.u[3] = f2b(f.w);
    ((uint2*)xb)[i] = o.v;
  } else if (bid < 9216) {
    // Wv [1024][1024] fp32 -> Wt2 rows [1024,2048) = Wv^T bf16
    float (*tb)[33] = (float(*)[33])smem;
    const int t = bid - 8192;
    const int bx = t & 31, by = t >> 5;
    const int tx = tid & 31, ty = tid >> 5;   // 32 x 8
    const int xcol = bx * 32 + tx, y0 = by * 32;
    #pragma unroll
    for (int i = 0; i < 4; ++i)
      tb[ty + i * 8][tx] = Wv[(long long)(y0 + ty + i * 8) * 1024 + xcol];
    __syncthreads();
    unsigned short* O = Wt2 + 1024 * 1024;
    const int xo = by * 32 + tx, yo0 = bx * 32;
    #pragma unroll
    for (int i = 0; i < 4; ++i)
      O[(long long)(yo0 + ty + i * 8) * 1024 + xo] = f2b(tb[tx][ty + i * 8]);
  } else if (bid < 9472) {
    // M^T = Wk . Wq^T (64x64 tile), fp32 inputs converted in-register, bf16 MFMA
    const int t = bid - 9216;
    const int bx = t & 15, by = t >> 4;
    const int row0 = by * 64, col0 = bx * 64;
    const int wave = tid >> 6, lane = tid & 63;
    const int wr = wave >> 1, wc = wave & 1;
    const int l15 = lane & 15, lk = lane >> 4;
    const int sr = lane >> 3, sg = lane & 7;
    char* lA = smem;
    char* lB = smem + 8192;
    const int rA = wr * 32 + l15, cB = wc * 32 + l15;
    const int xorA = (rA & 7) << 4, xorB = (cB & 7) << 4;
    const int kb = lk * 16;
    f32x4 acc[2][2];
    #pragma unroll
    for (int m = 0; m < 2; ++m)
      #pragma unroll
      for (int n = 0; n < 2; ++n) acc[m][n] = (f32x4)0.0f;
    for (int kt = 0; kt < 16; ++kt) {
      const int kc = kt * 64;
      short8 va[2], vb[2];
      int rr[2];
      #pragma unroll
      for (int j = 0; j < 2; ++j) {
        const int ci = wave * 2 + j;
        const int r = ci * 8 + sr;
        rr[j] = r;
        const float* pa = Wk + (long long)(row0 + r) * 1024 + kc + sg * 8;
        const float* pb = Wq + (long long)(col0 + r) * 1024 + kc + sg * 8;
        const float4 a0 = *(const float4*)pa, a1 = *(const float4*)(pa + 4);
        const float4 b0 = *(const float4*)pb, b1 = *(const float4*)(pb + 4);
        va[j][0] = (short)f2b(a0.x); va[j][1] = (short)f2b(a0.y);
        va[j][2] = (short)f2b(a0.z); va[j][3] = (short)f2b(a0.w);
        va[j][4] = (short)f2b(a1.x); va[j][5] = (short)f2b(a1.y);
        va[j][6] = (short)f2b(a1.z); va[j][7] = (short)f2b(a1.w);
        vb[j][0] = (short)f2b(b0.x); vb[j][1] = (short)f2b(b0.y);
        vb[j][2] = (short)f2b(b0.z); vb[j][3] = (short)f2b(b0.w);
        vb[j][4] = (short)f2b(b1.x); vb[j][5] = (short)f2b(b1.y);
        vb[j][6] = (short)f2b(b1.z); vb[j][7] = (short)f2b(b1.w);
      }
      __syncthreads();   // prev iter's LDS reads complete
      #pragma unroll
      for (int j = 0; j < 2; ++j) {
        const int off = rr[j] * 128 + ((sg * 16) ^ ((rr[j] & 7) << 4));
        *(short8*)(lA + off) = va[j];
        *(short8*)(lB + off) = vb[j];
      }
      __syncthreads();
      #pragma unroll
      for (int ks = 0; ks < 2; ++ks) {
        short8 af[2], bf[2];
        #pragma unroll
        for (int m = 0; m < 2; ++m)
          af[m] = *(const short8*)(lA + (rA + m * 16) * 128 + ((ks * 64 + kb) ^ xorA));
        #pragma unroll
        for (int n = 0; n < 2; ++n)
          bf[n] = *(const short8*)(lB + (cB + n * 16) * 128 + ((ks * 64 + kb) ^ xorB));
        #pragma unroll
        for (int m = 0; m < 2; ++m)
          #pragma unroll
          for (int n = 0; n < 2; ++n)
            acc[m][n] = __builtin_amdgcn_mfma_f32_16x16x32_bf16(af[m], bf[n], acc[m][n], 0, 0, 0);
      }
    }
    const int orow = row0 + wr * 32 + lk * 4;
    const int ocol = col0 + wc * 32 + l15;
    #pragma unroll
    for (int m = 0; m < 2; ++m)
      #pragma unroll
      for (int r = 0; r < 4; ++r)
        #pragma unroll
        for (int n = 0; n < 2; ++n)
          Wt2[(long long)(orow + m * 16 + r) * 1024 + ocol + n * 16] = f2b(acc[m][n][r]);
  } else {
    const int i = (bid - 9472) * 256 + tid;   // 8192 floats
    sums[i] = 0.f;
  }
}

// ==================== 256x256 8-phase GEMM machinery ====================
#define STG(buf, isB, half, kt) do {                                           \
    const unsigned short* _s = (isB) ? Bz : Az;                                \
    const int _ld = (isB) ? ldb : lda;                                         \
    const int _b0 = (isB) ? col0 : row0;                                       \
    char* _d = lds + (buf) * 65536 + (isB) * 32768 + (half) * 16384;           \
    _Pragma("unroll")                                                          \
    for (int _i = 0; _i < 2; ++_i) {                                           \
      const int _c = wave * 2 + _i;                                            \
      const int _row = (half) * 128 + _c * 8 + srow;                           \
      gload16(_s + (long long)(_b0 + _row) * _ld + (kt) * 64 + sgrp * 8,       \
              _d + _c * 1024);                                                 \
    } } while (0)

#define LDA8(dst, buf, mh) do {                                                \
    _Pragma("unroll")                                                          \
    for (int _m = 0; _m < 4; ++_m) {                                           \
      const int _r = wr * 128 + ((mh) * 4 + _m) * 16 + (lane & 15);            \
      const char* _p = lds + (buf) * 65536 + _r * 128;                         \
      const int _x = (_r & 7) << 4;                                            \
      dst[_m][0] = *(const short8*)(_p + ((kbyte) ^ _x));                      \
      dst[_m][1] = *(const short8*)(_p + ((64 + kbyte) ^ _x));                 \
    } } while (0)

#define LDB4(dst, buf, nh) do {                                                \
    _Pragma("unroll")                                                          \
    for (int _n = 0; _n < 2; ++_n) {                                           \
      const int _r = wc * 64 + ((nh) * 2 + _n) * 16 + (lane & 15);             \
      const char* _p = lds + (buf) * 65536 + 32768 + _r * 128;                 \
      const int _x = (_r & 7) << 4;                                            \
      dst[_n][0] = *(const short8*)(_p + ((kbyte) ^ _x));                      \
      dst[_n][1] = *(const short8*)(_p + ((64 + kbyte) ^ _x));                 \
    } } while (0)

#define MFMA16(mh, nh, av, bv) do {                                            \
    __builtin_amdgcn_s_setprio(1);                                             \
    _Pragma("unroll") for (int _n = 0; _n < 2; ++_n)                           \
    _Pragma("unroll") for (int _m = 0; _m < 4; ++_m)                           \
    _Pragma("unroll") for (int _k = 0; _k < 2; ++_k)                           \
      acc[(mh)*4+_m][(nh)*2+_n] = __builtin_amdgcn_mfma_f32_16x16x32_bf16(     \
          av[_m][_k], bv[_n][_k], acc[(mh)*4+_m][(nh)*2+_n], 0, 0, 0);         \
    __builtin_amdgcn_s_setprio(0);                                             \
  } while (0)

#define BAR() __builtin_amdgcn_s_barrier()
#define VM4() asm volatile("s_waitcnt vmcnt(4)" ::: "memory")
#define VM0() asm volatile("s_waitcnt vmcnt(0)" ::: "memory")

#define GEMM8_BODY(NT)                                                         \
  f32x4 acc[8][4];                                                             \
  _Pragma("unroll")                                                            \
  for (int m = 0; m < 8; ++m)                                                  \
    _Pragma("unroll")                                                          \
    for (int n = 0; n < 4; ++n) acc[m][n] = (f32x4)0.0f;                       \
  short8 a[4][2], b0[2][2], b1[2][2];                                          \
  STG(0, 1, 0, 0); STG(0, 1, 1, 0); STG(0, 0, 0, 0); STG(0, 0, 1, 0);          \
  STG(1, 1, 0, 1); STG(1, 1, 1, 1);                                            \
  VM4(); BAR();                                                                \
  for (int t = 0; t < (NT); ++t) {                                             \
    const bool pf = (t < (NT) - 1);                                            \
    LDA8(a, 0, 0); LDB4(b0, 0, 0);                                             \
    STG(1, 0, 0, 2 * t + 1);                                                   \
    BAR(); MFMA16(0, 0, a, b0); BAR();                                         \
    LDB4(b1, 0, 1);                                                            \
    STG(1, 0, 1, 2 * t + 1);                                                   \
    BAR(); MFMA16(0, 1, a, b1); BAR();                                         \
    LDA8(a, 0, 1);                                                             \
    if (pf) STG(0, 1, 0, 2 * t + 2);                                           \
    BAR(); MFMA16(1, 1, a, b1); BAR();                                         \
    if (pf) STG(0, 1, 1, 2 * t + 2);                                           \
    BAR(); MFMA16(1, 0, a, b0);                                                \
    if (pf) VM4(); else VM0();                                                 \
    BAR();                                                                     \
    LDA8(a, 1, 0); LDB4(b0, 1, 0);                                             \
    if (pf) STG(0, 0, 0, 2 * t + 2);                                           \
    BAR(); MFMA16(0, 0, a, b0); BAR();                                         \
    LDB4(b1, 1, 1);                                                            \
    if (pf) STG(0, 0, 1, 2 * t + 2);                                           \
    BAR(); MFMA16(0, 1, a, b1); BAR();                                         \
    LDA8(a, 1, 1);                                                             \
    if (pf) STG(1, 1, 0, 2 * t + 3);                                           \
    BAR(); MFMA16(1, 1, a, b1); BAR();                                         \
    if (pf) STG(1, 1, 1, 2 * t + 3);                                           \
    BAR(); MFMA16(1, 0, a, b0);                                                \
    if (pf) VM4();                                                             \
    BAR();                                                                     \
  }

// ---- [y|V] = x . [M^T ; Wv^T]^T, 256 blocks; y bf16 + Vt transposed out ----
__global__ __launch_bounds__(512, 2) void gemm8_yv(
    const unsigned short* __restrict__ A, const unsigned short* __restrict__ Bt,
    unsigned short* __restrict__ y, unsigned short* __restrict__ vt)
{
  const int row0 = blockIdx.y * 256;
  const int col0 = blockIdx.x * 256;
  const unsigned short* Az = A;
  const unsigned short* Bz = Bt;
  const int lda = 1024, ldb = 1024;

  __shared__ __align__(16) char lds[131072];

  const int tid = threadIdx.x;
  const int wave = tid >> 6, lane = tid & 63;
  const int wr = wave >> 2, wc = wave & 3;
  const int srow = lane >> 3, sgrp = (lane & 7) ^ srow;
  const int kbyte = (lane >> 4) * 16;

  GEMM8_BODY(8)

  const int orow = row0 + wr * 128 + ((lane >> 4) << 2);
  const int ocol = col0 + wc * 64 + (lane & 15);
  if (col0 < 1024) {
    #pragma unroll
    for (int m = 0; m < 8; ++m)
      #pragma unroll
      for (int r = 0; r < 4; ++r) {
        const int rg = orow + m * 16 + r;
        #pragma unroll
        for (int n = 0; n < 4; ++n)
          y[(long long)rg * 1024 + ocol + n * 16] = f2b(acc[m][n][r]);
      }
  } else {
    const int b = row0 >> 11;
    const int t0 = (row0 & 2047) + wr * 128 + ((lane >> 4) << 2);
    const int d0 = (col0 - 1024) + wc * 64 + (lane & 15);
    #pragma unroll
    for (int n = 0; n < 4; ++n) {
      unsigned short* vrow = vt + ((long long)b * 1024 + d0 + n * 16) * 2048 + t0;
      #pragma unroll
      for (int m = 0; m < 8; ++m) {
        short4v v;
        v[0] = (short)f2b(acc[m][n][0]);
        v[1] = (short)f2b(acc[m][n][1]);
        v[2] = (short)f2b(acc[m][n][2]);
        v[3] = (short)f2b(acc[m][n][3]);
        *(short4v*)(vrow + m * 16) = v;
      }
    }
  }
}

// ---- P = exp((y x^T)/32) causal + rowsum atomics ----
__global__ __launch_bounds__(512, 2) void gemm8_p(
    const unsigned short* __restrict__ A, const unsigned short* __restrict__ Bt,
    unsigned short* __restrict__ outp, float* __restrict__ sums)
{
  const int z = blockIdx.z;
  const int row0 = blockIdx.y * 256;
  const int col0 = blockIdx.x * 256;
  if (col0 > row0 + 255) return;

  const unsigned short* Az = A + (long long)z * (2048 * 1024);
  const unsigned short* Bz = Bt + (long long)z * (2048 * 1024);
  const int lda = 1024, ldb = 1024;

  __shared__ __align__(16) char lds[131072];

  const int tid = threadIdx.x;
  const int wave = tid >> 6, lane = tid & 63;
  const int wr = wave >> 2, wc = wave & 3;
  const int srow = lane >> 3, sgrp = (lane & 7) ^ srow;
  const int kbyte = (lane >> 4) * 16;

  GEMM8_BODY(8)

  const int orow = row0 + wr * 128 + ((lane >> 4) << 2);
  const int ocol = col0 + wc * 64 + (lane & 15);
  unsigned short* out = outp + (long long)z * (2048 * 2048);
  #pragma unroll
  for (int m = 0; m < 8; ++m)
    #pragma unroll
    for (int r = 0; r < 4; ++r) {
      const int rg = orow + m * 16 + r;
      float rs = 0.f;
      #pragma unroll
      for (int n = 0; n < 4; ++n) {
        const int cg = ocol + n * 16;
        float p = (cg > rg) ? 0.0f : __expf(acc[m][n][r] * 0.03125f);
        rs += p;
        out[(long long)rg * 2048 + cg] = f2b(p);
      }
      #pragma unroll
      for (int off = 1; off < 16; off <<= 1) rs += __shfl_xor(rs, off);
      if ((lane & 15) == 0) atomicAdd(&sums[(long long)z * 2048 + rg], rs);
    }
}

// ==================== 128x128 2-phase PV (causal K-bound, longest-first) ====================
__global__ __launch_bounds__(256) void gemm_pv(
    const unsigned short* __restrict__ P, const unsigned short* __restrict__ Vt,
    float* __restrict__ out, const float* __restrict__ sums)
{
  const int z = blockIdx.z;
  const int row0 = (15 - blockIdx.y) * 128;   // longest-K blocks dispatch first
  const int col0 = blockIdx.x * 128;

  const unsigned short* Az = P + (long long)z * (2048 * 2048);
  const unsigned short* Bz = Vt + (long long)z * (1024 * 2048);

  __shared__ __align__(16) char lds[32768];

  const int tid = threadIdx.x;
  const int wave = tid >> 6;
  const int lane = tid & 63;
  const int wr = wave >> 1, wc = wave & 1;
  const int l15 = lane & 15, lk = lane >> 4;

  const int srow = lane >> 3;
  const int sgrp = (lane & 7) ^ srow;

  const int rA = wr * 64 + l15;
  const int cB = wc * 64 + l15;
  const int kb = lk * 16;
  const int xorA = (rA & 7) << 4;
  const int xorB = (cB & 7) << 4;

  f32x4 acc[4][4];
  #pragma unroll
  for (int m = 0; m < 4; ++m)
    #pragma unroll
    for (int n = 0; n < 4; ++n) acc[m][n] = (f32x4)0.0f;

  const int nkt = (row0 + 128) >> 6;

  for (int kt = 0; kt < nkt; ++kt) {
    const int kc = kt * 64;
    #pragma unroll
    for (int i = 0; i < 4; ++i) {
      const int ci = wave * 4 + i;
      gload16(Az + (long long)(row0 + ci * 8 + srow) * 2048 + kc + sgrp * 8,
              lds + ci * 1024);
      gload16(Bz + (long long)(col0 + ci * 8 + srow) * 2048 + kc + sgrp * 8,
              lds + 16384 + ci * 1024);
    }
    __syncthreads();
    #pragma unroll
    for (int ks = 0; ks < 2; ++ks) {
      short8 af[4], bfr[4];
      #pragma unroll
      for (int m = 0; m < 4; ++m)
        af[m] = *(const short8*)(lds + (rA + m * 16) * 128 + ((ks * 64 + kb) ^ xorA));
      #pragma unroll
      for (int n = 0; n < 4; ++n)
        bfr[n] = *(const short8*)(lds + 16384 + (cB + n * 16) * 128 + ((ks * 64 + kb) ^ xorB));
      #pragma unroll
      for (int m = 0; m < 4; ++m)
        #pragma unroll
        for (int n = 0; n < 4; ++n)
          acc[m][n] = __builtin_amdgcn_mfma_f32_16x16x32_bf16(af[m], bfr[n], acc[m][n], 0, 0, 0);
    }
    __syncthreads();
  }

  const int orow = row0 + wr * 64 + lk * 4;
  const int ocol = col0 + wc * 64 + l15;
  const float* sz = sums + (long long)z * 2048;
  float* oz = out + (long long)z * (2048 * 1024);
  #pragma unroll
  for (int m = 0; m < 4; ++m)
    #pragma unroll
    for (int r = 0; r < 4; ++r) {
      const int rg = orow + m * 16 + r;
      const float iv = 1.0f / sz[rg];
      #pragma unroll
      for (int n = 0; n < 4; ++n)
        oz[(long long)rg * 1024 + ocol + n * 16] = acc[m][n][r] * iv;
    }
}

extern "C" void kernel_launch(void* const* d_in, const int* in_sizes, int n_in,
                              void* d_out, int out_size, void* d_ws, size_t ws_size,
                              hipStream_t stream) {
  (void)in_sizes; (void)n_in; (void)out_size; (void)ws_size;
  const float* x  = (const float*)d_in[0];
  const float* Wq = (const float*)d_in[1];
  const float* Wk = (const float*)d_in[2];
  const float* Wv = (const float*)d_in[3];
  float* out = (float*)d_out;

  char* ws = (char*)d_ws;
  unsigned short* xb  = (unsigned short*)(ws);               // 8192x1024 bf16
  unsigned short* Wt2 = (unsigned short*)(ws + 16777216);    // [2048][1024]: M^T ; Wv^T
  unsigned short* y   = (unsigned short*)(ws + 20971520);    // 8192x1024 bf16
  unsigned short* Vt  = (unsigned short*)(ws + 37748736);    // 4x1024x2048 bf16
  unsigned short* P   = (unsigned short*)(ws + 54525952);    // 4x2048x2048 bf16
  float*          sums = (float*)(ws + 88080384);            // 4x2048 fp32

  // 1. prep: cvt x, transpose Wv, M^T = Wk.Wq^T (fp32-direct), zero sums
  prep<<<9504, 256, 0, stream>>>(x, Wq, Wk, Wv, xb, Wt2, sums);

  // 2. [y | V] = x . [M^T ; Wv^T]^T  (256 gemm8 blocks = exactly 1 round)
  gemm8_yv<<<dim3(8, 32), 512, 0, stream>>>(xb, Wt2, y, Vt);

  // 3. P = exp((y x^T)/32) causal, unnormalized bf16 + rowsums
  gemm8_p<<<dim3(8, 8, 4), 512, 0, stream>>>(y, xb, P, sums);

  // 4. context = (P Vt^T) / rowsum  (fp32 out, causal K-bound, longest-first)
  gemm_pv<<<dim3(8, 16, 4), 256, 0, stream>>>(P, Vt, out, sums);
}